// Round 1
// baseline (89.065 us; speedup 1.0000x reference)
//
#include <hip/hip_runtime.h>
#include <cmath>

typedef unsigned short u16;
typedef __bf16 bf16x8 __attribute__((ext_vector_type(8)));
typedef float f32x4 __attribute__((ext_vector_type(4)));
typedef unsigned short u16x8 __attribute__((ext_vector_type(8)));
typedef unsigned short u16x4 __attribute__((ext_vector_type(4)));

#define BATCH 16384
#define NTREE 32
#define NINT 63
#define NLEAF 64
#define FDIM 256
#define MT 64
#define LDA 264  // 256+8 ushorts -> row stride 528B (16B aligned, bank stride 4 -> 2-way max, free)

__device__ __forceinline__ u16 f2bf(float f) {
    unsigned int x = __float_as_uint(f);
    x += 0x7fffu + ((x >> 16) & 1u);   // round-to-nearest-even
    return (u16)(x >> 16);
}

__global__ void convert_kernel(const float* __restrict__ x, const float* __restrict__ W,
                               u16* __restrict__ xb, u16* __restrict__ Wb) {
    int idx = blockIdx.x * blockDim.x + threadIdx.x;
    int stride = gridDim.x * blockDim.x;
    const int NXQ = BATCH * FDIM / 4;
    for (int i = idx; i < NXQ; i += stride) {
        float4 v = ((const float4*)x)[i];
        u16x4 o = { f2bf(v.x), f2bf(v.y), f2bf(v.z), f2bf(v.w) };
        ((u16x4*)xb)[i] = o;
    }
    // Wb layout: [tree][64 nodes (63 real + 1 zero pad)][256 features], bf16
    const int NWQ = NTREE * NLEAF * FDIM / 4;
    for (int i = idx; i < NWQ; i += stride) {
        int t = i / (NLEAF * FDIM / 4);
        int r = i % (NLEAF * FDIM / 4);
        int node = r / (FDIM / 4);
        int kq = r % (FDIM / 4);
        float4 v = make_float4(0.f, 0.f, 0.f, 0.f);
        if (node < NINT) v = ((const float4*)(W + ((size_t)t * NINT + node) * FDIM))[kq];
        u16x4 o = { f2bf(v.x), f2bf(v.y), f2bf(v.z), f2bf(v.w) };
        ((u16x4*)Wb)[i] = o;
    }
}

__global__ __launch_bounds__(256) void softgbm_main(
    const u16* __restrict__ xb, const u16* __restrict__ Wb,
    const float* __restrict__ bg, const float* __restrict__ phig,
    float* __restrict__ partial) {
    __shared__ u16 Alds[MT * LDA];
    __shared__ u16 Blds[NLEAF * LDA];

    const int tid = threadIdx.x;
    const int t = blockIdx.y;
    const int m0 = blockIdx.x * MT;

    // Stage x tile (64x256) and W tree (64x256) into LDS, 16B chunks, coalesced.
    const u16x8* xg = (const u16x8*)(xb + (size_t)m0 * FDIM);
    const u16x8* wg = (const u16x8*)(Wb + (size_t)t * NLEAF * FDIM);
    for (int c = tid; c < MT * FDIM / 8; c += 256) {
        int row = c >> 5, col = c & 31;
        *(u16x8*)&Alds[row * LDA + col * 8] = xg[c];
        *(u16x8*)&Blds[row * LDA + col * 8] = wg[c];
    }
    __syncthreads();

    const int lane = tid & 63;
    const int w = tid >> 6;          // wave id: row strip w*16..w*16+15
    const int frow = lane & 15;
    const int fk = (lane >> 4) * 8;  // 8 contiguous K per lane

    f32x4 acc[4] = {};
    #pragma unroll
    for (int k0 = 0; k0 < FDIM; k0 += 32) {
        bf16x8 a = *(const bf16x8*)&Alds[(w * 16 + frow) * LDA + k0 + fk];
        #pragma unroll
        for (int ct = 0; ct < 4; ++ct) {
            bf16x8 bb = *(const bf16x8*)&Blds[(ct * 16 + frow) * LDA + k0 + fk];
            acc[ct] = __builtin_amdgcn_mfma_f32_16x16x32_bf16(a, bb, acc[ct], 0, 0, 0);
        }
    }

    float bv[4];
    #pragma unroll
    for (int ct = 0; ct < 4; ++ct) {
        int col = ct * 16 + frow;
        bv[ct] = (col < NINT) ? bg[t * NINT + col] : 0.f;
    }

    __syncthreads();                 // all LDS frag reads done; reuse Alds for probs
    float* p = (float*)Alds;         // [64 rows][65] f32 (16.6KB < 33.7KB)
    #pragma unroll
    for (int ct = 0; ct < 4; ++ct) {
        #pragma unroll
        for (int j = 0; j < 4; ++j) {
            int row = w * 16 + (lane >> 4) * 4 + j;   // C/D: row=(lane>>4)*4+reg
            int col = ct * 16 + frow;                 //      col=lane&15
            float z = acc[ct][j] + bv[ct];
            p[row * 65 + col] = 1.f / (1.f + expf(-z));
        }
    }
    __syncthreads();

    // Tree eval: thread = (row, quarter-of-leaves). Leaf l bits MSB-first select path.
    int row = tid >> 2, q = tid & 3;
    const float* pr = p + row * 65;
    const float* ph = phig + t * NLEAF;
    float s = 0.f;
    #pragma unroll
    for (int i = 0; i < 16; ++i) {
        int l = q * 16 + i;
        float mu = 1.f;
        int idxl = 0;
        #pragma unroll
        for (int d = 0; d < 6; ++d) {
            int bit = (l >> (5 - d)) & 1;
            float pp = pr[(1 << d) - 1 + idxl];
            mu *= bit ? pp : (1.f - pp);
            idxl = idxl * 2 + bit;
        }
        s += mu * ph[l];
    }
    s += __shfl_xor(s, 1);
    s += __shfl_xor(s, 2);
    if (q == 0) partial[(size_t)t * BATCH + m0 + row] = s;
}

__global__ void reduce_kernel(const float* __restrict__ partial, float* __restrict__ out) {
    int i = blockIdx.x * 256 + threadIdx.x;
    float s = 0.f;
    #pragma unroll
    for (int t = 0; t < NTREE; ++t) s += partial[(size_t)t * BATCH + i];
    out[i] = 0.1f * s;
}

extern "C" void kernel_launch(void* const* d_in, const int* in_sizes, int n_in,
                              void* d_out, int out_size, void* d_ws, size_t ws_size,
                              hipStream_t stream) {
    const float* x   = (const float*)d_in[0];
    const float* W   = (const float*)d_in[1];
    const float* b   = (const float*)d_in[2];
    const float* phi = (const float*)d_in[3];
    float* out = (float*)d_out;

    u16* xb = (u16*)d_ws;                                  // 16384*256 bf16 = 8 MB
    u16* Wb = xb + (size_t)BATCH * FDIM;                   // 32*64*256 bf16 = 1 MB
    float* partial = (float*)(Wb + (size_t)NTREE * NLEAF * FDIM);  // 32*16384 f32 = 2 MB

    convert_kernel<<<2048, 256, 0, stream>>>(x, W, xb, Wb);
    softgbm_main<<<dim3(BATCH / MT, NTREE), 256, 0, stream>>>(xb, Wb, b, phi, partial);
    reduce_kernel<<<BATCH / 256, 256, 0, stream>>>(partial, out);
}

// Round 2
// 66.708 us; speedup vs baseline: 1.3351x; 1.3351x over previous
//
#include <hip/hip_runtime.h>
#include <cmath>

typedef unsigned short u16;
typedef __bf16 bf16x8 __attribute__((ext_vector_type(8)));
typedef float f32x4 __attribute__((ext_vector_type(4)));
typedef unsigned short u16x8 __attribute__((ext_vector_type(8)));
typedef unsigned short u16x4 __attribute__((ext_vector_type(4)));

#define BATCH 16384
#define NTREE 32
#define NINT 63
#define NLEAF 64
#define FDIM 256
#define MT 128          // rows per block
#define TPB 2           // trees per block

__device__ __forceinline__ u16 f2bf(float f) {
    unsigned int x = __float_as_uint(f);
    x += 0x7fffu + ((x >> 16) & 1u);   // round-to-nearest-even
    return (u16)(x >> 16);
}

__global__ void convert_kernel(const float* __restrict__ x, const float* __restrict__ W,
                               u16* __restrict__ xb, u16* __restrict__ Wb) {
    int idx = blockIdx.x * blockDim.x + threadIdx.x;
    int stride = gridDim.x * blockDim.x;
    const int NXQ = BATCH * FDIM / 4;
    for (int i = idx; i < NXQ; i += stride) {
        float4 v = ((const float4*)x)[i];
        u16x4 o = { f2bf(v.x), f2bf(v.y), f2bf(v.z), f2bf(v.w) };
        ((u16x4*)xb)[i] = o;
    }
    // Wb layout: [tree][64 nodes (63 real + 1 zero pad)][256 features], bf16
    const int NWQ = NTREE * NLEAF * FDIM / 4;
    for (int i = idx; i < NWQ; i += stride) {
        int t = i / (NLEAF * FDIM / 4);
        int r = i % (NLEAF * FDIM / 4);
        int node = r / (FDIM / 4);
        int kq = r % (FDIM / 4);
        float4 v = make_float4(0.f, 0.f, 0.f, 0.f);
        if (node < NINT) v = ((const float4*)(W + ((size_t)t * NINT + node) * FDIM))[kq];
        u16x4 o = { f2bf(v.x), f2bf(v.y), f2bf(v.z), f2bf(v.w) };
        ((u16x4*)Wb)[i] = o;
    }
}

// Block: 256 threads = 4 waves. Covers MT=128 batch rows x 2 trees (128 node-cols).
// Wave (wr,wc): rows wr*64..+63, tree wc (cols wc*64..+63). 4x4 frag tile, K chunked by 64.
// LDS A/B tiles are XOR-swizzled at 16B-chunk granularity: phys_chunk = cc ^ (row&7)
// -> both ds_write_b128 staging and ds_read_b128 frag reads hit the 8-phase b128 floor
// (conflict-free).
__global__ __launch_bounds__(256) void softgbm_main(
    const u16* __restrict__ xb, const u16* __restrict__ Wb,
    const float* __restrict__ bg, const float* __restrict__ phig,
    float* __restrict__ partial) {
    union ShMem {
        struct { u16 A[MT * 64]; u16 B[MT * 64]; } s;            // 16KB + 16KB
        struct { float p[TPB][MT][65]; float phi[TPB][64]; } e;  // 66.5KB + 0.5KB
    };
    __shared__ ShMem sh;

    const int tid = threadIdx.x;
    const int t0 = blockIdx.y * TPB;
    const int m0 = blockIdx.x * MT;

    // ---- staging addressing: thread -> (row = tid>>3 + 32*i, cc = tid&7) 16B chunks
    const int srow = tid >> 3, scc = tid & 7;
    const u16* ag = xb + (size_t)(m0 + srow) * FDIM + scc * 8;
    const u16* wg = Wb + (size_t)(t0 * NLEAF + srow) * FDIM + scc * 8;
    const int lofs = (srow * 8 + (scc ^ (srow & 7))) * 8;   // u16 offset, +2048 per i

    // ---- wave/frag constants
    const int lane = tid & 63, w = tid >> 6;
    const int wr = w >> 1, wc = w & 1;
    const int frow = lane & 15, lg = lane >> 4, f7 = frow & 7;
    int aoff[4], boff[4];
    #pragma unroll
    for (int ar = 0; ar < 4; ++ar)
        aoff[ar] = ((wr * 64 + ar * 16 + frow) * 8 + (lg ^ f7)) * 8;
    #pragma unroll
    for (int bc = 0; bc < 4; ++bc)
        boff[bc] = ((wc * 64 + bc * 16 + frow) * 8 + (lg ^ f7)) * 8;

    // bias values for this wave's cols (loaded early, lives in regs)
    float bv[4];
    #pragma unroll
    for (int bc = 0; bc < 4; ++bc) {
        int col = bc * 16 + frow;
        bv[bc] = (col < NINT) ? bg[(t0 + wc) * NINT + col] : 0.f;
    }
    // stage phi into LDS (region beyond the 32KB staging buffers -> no overlap)
    if (tid < TPB * 64)
        sh.e.phi[tid >> 6][tid & 63] = phig[(t0 + (tid >> 6)) * NLEAF + (tid & 63)];

    // ---- chunk 0 load + store
    u16x8 ra[4], rb[4];
    #pragma unroll
    for (int i = 0; i < 4; ++i) {
        ra[i] = *(const u16x8*)(ag + i * 32 * FDIM);
        rb[i] = *(const u16x8*)(wg + i * 32 * FDIM);
    }
    #pragma unroll
    for (int i = 0; i < 4; ++i) {
        *(u16x8*)&sh.s.A[lofs + i * 2048] = ra[i];
        *(u16x8*)&sh.s.B[lofs + i * 2048] = rb[i];
    }
    __syncthreads();

    f32x4 acc[4][4] = {};
    #pragma unroll
    for (int c = 0; c < 4; ++c) {
        if (c < 3) {   // prefetch next K-chunk into regs (overlaps with MFMA below)
            #pragma unroll
            for (int i = 0; i < 4; ++i) {
                ra[i] = *(const u16x8*)(ag + (c + 1) * 64 + i * 32 * FDIM);
                rb[i] = *(const u16x8*)(wg + (c + 1) * 64 + i * 32 * FDIM);
            }
        }
        #pragma unroll
        for (int ks = 0; ks < 2; ++ks) {
            bf16x8 af[4], bf_[4];
            #pragma unroll
            for (int ar = 0; ar < 4; ++ar) af[ar] = *(const bf16x8*)&sh.s.A[aoff[ar] ^ (ks * 32)];
            #pragma unroll
            for (int bc = 0; bc < 4; ++bc) bf_[bc] = *(const bf16x8*)&sh.s.B[boff[bc] ^ (ks * 32)];
            #pragma unroll
            for (int ar = 0; ar < 4; ++ar)
                #pragma unroll
                for (int bc = 0; bc < 4; ++bc)
                    acc[ar][bc] = __builtin_amdgcn_mfma_f32_16x16x32_bf16(af[ar], bf_[bc], acc[ar][bc], 0, 0, 0);
        }
        __syncthreads();
        if (c < 3) {
            #pragma unroll
            for (int i = 0; i < 4; ++i) {
                *(u16x8*)&sh.s.A[lofs + i * 2048] = ra[i];
                *(u16x8*)&sh.s.B[lofs + i * 2048] = rb[i];
            }
            __syncthreads();
        }
    }

    // ---- sigmoid + scatter probs to LDS (f32, stride 65 -> read side conflict-free)
    #pragma unroll
    for (int ar = 0; ar < 4; ++ar)
        #pragma unroll
        for (int bc = 0; bc < 4; ++bc)
            #pragma unroll
            for (int j = 0; j < 4; ++j) {
                int row = wr * 64 + ar * 16 + lg * 4 + j;   // C/D: row=(lane>>4)*4+reg
                int col = bc * 16 + frow;                   //      col=lane&15
                float z = acc[ar][bc][j] + bv[bc];
                sh.e.p[wc][row][col] = __builtin_amdgcn_rcpf(1.f + __expf(-z));
            }
    __syncthreads();

    // ---- tree eval: thread = (tree-half, row). Level expansion in registers.
    {
        const int th = tid >> 7, row = tid & (MT - 1);
        const float* pr = sh.e.p[th][row];
        const float* pf = sh.e.phi[th];
        float mu[32];
        float p0 = pr[0];
        mu[0] = 1.f - p0; mu[1] = p0;
        #pragma unroll
        for (int d = 1; d < 5; ++d) {
            int n = 1 << d;
            int off = n - 1;
            #pragma unroll
            for (int i = n - 1; i >= 0; --i) {
                float p = pr[off + i];
                float m = mu[i];
                float t = m * p;
                mu[2 * i + 1] = t;
                mu[2 * i] = m - t;
            }
        }
        float s = 0.f;
        #pragma unroll
        for (int i = 0; i < 32; ++i) {
            float p = pr[31 + i];
            float a = pf[2 * i], b2 = pf[2 * i + 1];
            s += mu[i] * (a + p * (b2 - a));
        }
        partial[(size_t)(t0 + th) * BATCH + m0 + row] = s;
    }
}

__global__ void reduce_kernel(const float* __restrict__ partial, float* __restrict__ out) {
    int i = blockIdx.x * 256 + threadIdx.x;
    float s = 0.f;
    #pragma unroll
    for (int t = 0; t < NTREE; ++t) s += partial[(size_t)t * BATCH + i];
    out[i] = 0.1f * s;
}

extern "C" void kernel_launch(void* const* d_in, const int* in_sizes, int n_in,
                              void* d_out, int out_size, void* d_ws, size_t ws_size,
                              hipStream_t stream) {
    const float* x   = (const float*)d_in[0];
    const float* W   = (const float*)d_in[1];
    const float* b   = (const float*)d_in[2];
    const float* phi = (const float*)d_in[3];
    float* out = (float*)d_out;

    u16* xb = (u16*)d_ws;                                  // 16384*256 bf16 = 8 MB
    u16* Wb = xb + (size_t)BATCH * FDIM;                   // 32*64*256 bf16 = 1 MB
    float* partial = (float*)(Wb + (size_t)NTREE * NLEAF * FDIM);  // 32*16384 f32 = 2 MB

    convert_kernel<<<2048, 256, 0, stream>>>(x, W, xb, Wb);
    softgbm_main<<<dim3(BATCH / MT, NTREE / TPB), 256, 0, stream>>>(xb, Wb, b, phi, partial);
    reduce_kernel<<<BATCH / 256, 256, 0, stream>>>(partial, out);
}